// Round 5
// baseline (391.161 us; speedup 1.0000x reference)
//
#include <hip/hip_runtime.h>
#include <hip/hip_bf16.h>

#define EMBED_DIM 12
#define EPS 1e-12f
#define VPT 512      // voxels per tile
#define SLOT 13      // floats per voxel slot: 12 acc + scale_sum
#define BLOCK 256

// K1: CSR offsets from sorted voxel_ids + quantize table rows to
// biased-uint8 (q+128) x12 + fp32 scale, packed 16 B/row.
__global__ void prep_kernel(const int* __restrict__ vox,
                            int* __restrict__ starts,
                            const float* __restrict__ tab,
                            uint4* __restrict__ packed,
                            int T, int N, int rows) {
    int i = blockIdx.x * blockDim.x + threadIdx.x;

    if (i < rows) {
        const float4* rp = reinterpret_cast<const float4*>(tab + (size_t)i * EMBED_DIM);
        float4 a = rp[0], b = rp[1], c = rp[2];
        float vv[EMBED_DIM] = {a.x, a.y, a.z, a.w, b.x, b.y, b.z, b.w,
                               c.x, c.y, c.z, c.w};
        float am = 0.0f;
#pragma unroll
        for (int j = 0; j < EMBED_DIM; ++j) am = fmaxf(am, fabsf(vv[j]));
        float scale = am * (1.0f / 127.0f);
        float inv = (am > 0.0f) ? (127.0f / am) : 0.0f;
        unsigned int w[3] = {0u, 0u, 0u};
#pragma unroll
        for (int j = 0; j < EMBED_DIM; ++j) {
            int q = (int)rintf(vv[j] * inv);
            q = max(-127, min(127, q));
            unsigned int u = (unsigned int)(q + 128);   // [1,255]
            w[j >> 2] |= u << ((j & 3) * 8);
        }
        uint4 o;
        o.x = w[0]; o.y = w[1]; o.z = w[2]; o.w = __float_as_uint(scale);
        packed[i] = o;
    }

    if (i >= T) return;
    int cur = vox[i];
    int prev = (i == 0) ? -1 : vox[i - 1];
    for (int v = prev + 1; v <= cur; ++v) starts[v] = i;
    if (i == T - 1) {
        for (int v = cur + 1; v <= N; ++v) starts[v] = T;
    }
}

__device__ __forceinline__ float ubyte_f(unsigned int w, int k) {
    // (float)((w >> 8k) & 0xff) -> v_cvt_f32_ubyte{k}
    return (float)((w >> (k * 8)) & 0xffu);
}

__device__ __forceinline__ void acc_one(float* lacc, int base,
                                        const uint4 p, float sc) {
#pragma unroll
    for (int j = 0; j < 4; ++j) {
        atomicAdd(&lacc[base + j],     sc * ubyte_f(p.x, j));
        atomicAdd(&lacc[base + 4 + j], sc * ubyte_f(p.y, j));
        atomicAdd(&lacc[base + 8 + j], sc * ubyte_f(p.z, j));
    }
    atomicAdd(&lacc[base + 12], sc);
}

// K2: tile of 512 voxels per block. Uniform token sweep (2 consecutive
// tokens/thread, int2 loads), biased-ubyte decode, LDS atomic accumulate,
// then in-block mean+L2-normalize and coalesced store.
__global__ void __launch_bounds__(BLOCK)
pool_lds_kernel(const uint4* __restrict__ packed,
                const int* __restrict__ seg,
                const int* __restrict__ vox,
                const int* __restrict__ starts,
                float* __restrict__ out, int N) {
    __shared__ float lacc[VPT * SLOT];
    int v0 = blockIdx.x * VPT;
    for (int i = threadIdx.x; i < VPT * SLOT; i += BLOCK) lacc[i] = 0.0f;
    __syncthreads();

    int vend = min(v0 + VPT, N);
    int s = starts[v0];
    int e = starts[vend];
    int t0 = s & ~1;  // even base so int2 loads are 8B-aligned

    for (int b = t0 + (int)threadIdx.x * 2; b < e; b += 2 * BLOCK) {
        int2 sg, vx;
        bool ok1 = (b + 1 < e);
        if (ok1) {
            sg = *reinterpret_cast<const int2*>(seg + b);
            vx = *reinterpret_cast<const int2*>(vox + b);
        } else {
            sg.x = seg[b]; sg.y = sg.x;
            vx.x = vox[b]; vx.y = -1;
        }
        bool ok0 = (b >= s);
        uint4 p0 = packed[sg.x];
        uint4 p1 = packed[sg.y];
        float sc0 = __uint_as_float(p0.w);
        float sc1 = __uint_as_float(p1.w);

        if (ok0 && ok1 && (vx.x == vx.y)) {
            int base = (vx.x - v0) * SLOT;
#pragma unroll
            for (int j = 0; j < 4; ++j) {
                atomicAdd(&lacc[base + j],
                          sc0 * ubyte_f(p0.x, j) + sc1 * ubyte_f(p1.x, j));
                atomicAdd(&lacc[base + 4 + j],
                          sc0 * ubyte_f(p0.y, j) + sc1 * ubyte_f(p1.y, j));
                atomicAdd(&lacc[base + 8 + j],
                          sc0 * ubyte_f(p0.z, j) + sc1 * ubyte_f(p1.z, j));
            }
            atomicAdd(&lacc[base + 12], sc0 + sc1);
        } else {
            if (ok0) acc_one(lacc, (vx.x - v0) * SLOT, p0, sc0);
            if (ok1) acc_one(lacc, (vx.y - v0) * SLOT, p1, sc1);
        }
    }
    __syncthreads();

    for (int r = (int)threadIdx.x; r < VPT; r += BLOCK) {
        int v = v0 + r;
        if (v >= N) break;
        int cs = starts[v];
        int ce = starts[v + 1];
        float scsum = lacc[r * SLOT + 12];
        float inv_cnt = 1.0f / fmaxf((float)(ce - cs), 1.0f);
        float m[EMBED_DIM];
        float nrm2 = 0.0f;
#pragma unroll
        for (int j = 0; j < EMBED_DIM; ++j) {
            float x = (lacc[r * SLOT + j] - 128.0f * scsum) * inv_cnt;
            m[j] = x;
            nrm2 += x * x;
        }
        float inv_nrm = 1.0f / fmaxf(sqrtf(nrm2), EPS);
        float4* orow = reinterpret_cast<float4*>(out + (size_t)v * EMBED_DIM);
        orow[0] = make_float4(m[0] * inv_nrm, m[1] * inv_nrm,
                              m[2] * inv_nrm, m[3] * inv_nrm);
        orow[1] = make_float4(m[4] * inv_nrm, m[5] * inv_nrm,
                              m[6] * inv_nrm, m[7] * inv_nrm);
        orow[2] = make_float4(m[8] * inv_nrm, m[9] * inv_nrm,
                              m[10] * inv_nrm, m[11] * inv_nrm);
    }
}

// Fallback (ws too small): one thread per voxel, fp32 table.
__global__ void pool_normalize_f32_kernel(const float* __restrict__ table,
                                          const int* __restrict__ seg,
                                          const int* __restrict__ starts,
                                          float* __restrict__ out,
                                          int N) {
    int v = blockIdx.x * blockDim.x + threadIdx.x;
    if (v >= N) return;
    int s = starts[v];
    int e = starts[v + 1];
    float acc[EMBED_DIM];
#pragma unroll
    for (int j = 0; j < EMBED_DIM; ++j) acc[j] = 0.0f;
    for (int t = s; t < e; ++t) {
        const float4* row =
            reinterpret_cast<const float4*>(table + (size_t)seg[t] * EMBED_DIM);
        float4 a = row[0], b = row[1], c = row[2];
        acc[0] += a.x; acc[1] += a.y; acc[2]  += a.z; acc[3]  += a.w;
        acc[4] += b.x; acc[5] += b.y; acc[6]  += b.z; acc[7]  += b.w;
        acc[8] += c.x; acc[9] += c.y; acc[10] += c.z; acc[11] += c.w;
    }
    float inv_cnt = 1.0f / fmaxf((float)(e - s), 1.0f);
    float nrm2 = 0.0f;
#pragma unroll
    for (int j = 0; j < EMBED_DIM; ++j) {
        acc[j] *= inv_cnt;
        nrm2 += acc[j] * acc[j];
    }
    float inv_nrm = 1.0f / fmaxf(sqrtf(nrm2), EPS);
#pragma unroll
    for (int j = 0; j < EMBED_DIM; ++j)
        out[(size_t)v * EMBED_DIM + j] = acc[j] * inv_nrm;
}

extern "C" void kernel_launch(void* const* d_in, const int* in_sizes, int n_in,
                              void* d_out, int out_size, void* d_ws, size_t ws_size,
                              hipStream_t stream) {
    const float* table = (const float*)d_in[0];
    const int* seg_ids = (const int*)d_in[1];
    const int* voxel_ids = (const int*)d_in[2];
    int N = out_size / EMBED_DIM;        // 1048576
    int T = in_sizes[1];                 // 8388608
    int rows = in_sizes[0] / EMBED_DIM;  // 50000

    size_t starts_bytes = (size_t)(N + 1) * sizeof(int);
    size_t starts_pad = (starts_bytes + 255) & ~(size_t)255;
    size_t packed_bytes = (size_t)rows * sizeof(uint4);
    bool use_q8 = ws_size >= starts_pad + packed_bytes;

    int* starts = (int*)d_ws;
    uint4* packed = (uint4*)((char*)d_ws + starts_pad);
    float* out = (float*)d_out;

    {
        int block = 256;
        int grid = (T + block - 1) / block;
        prep_kernel<<<grid, block, 0, stream>>>(voxel_ids, starts, table,
                                                use_q8 ? packed : (uint4*)starts,
                                                T, N, use_q8 ? rows : 0);
    }

    if (use_q8) {
        int grid = (N + VPT - 1) / VPT;   // 2048 tiles
        pool_lds_kernel<<<grid, BLOCK, 0, stream>>>(packed, seg_ids, voxel_ids,
                                                    starts, out, N);
    } else {
        int block = 256;
        int grid = (N + block - 1) / block;
        pool_normalize_f32_kernel<<<grid, block, 0, stream>>>(table, seg_ids,
                                                              starts, out, N);
    }
}

// Round 6
// 74.144 us; speedup vs baseline: 5.2757x; 5.2757x over previous
//
#include <hip/hip_runtime.h>
#include <hip/hip_bf16.h>

#define EMBED_DIM 12
#define EPS 1e-12f

// K1 (fused prep): CSR offsets from sorted voxel_ids + quantize table rows to
// biased-uint8 ((q+128) in [1,255]) x12 + fp32 scale, packed 16 B/row so a
// token's whole row gather is a single dwordx4 (one lane-address).
__global__ void prep_kernel(const int* __restrict__ vox,
                            int* __restrict__ starts,
                            const float* __restrict__ tab,
                            uint4* __restrict__ packed,
                            int T, int N, int rows) {
    int i = blockIdx.x * blockDim.x + threadIdx.x;

    if (i < rows) {
        const float4* rp = reinterpret_cast<const float4*>(tab + (size_t)i * EMBED_DIM);
        float4 a = rp[0], b = rp[1], c = rp[2];
        float vv[EMBED_DIM] = {a.x, a.y, a.z, a.w, b.x, b.y, b.z, b.w,
                               c.x, c.y, c.z, c.w};
        float am = 0.0f;
#pragma unroll
        for (int j = 0; j < EMBED_DIM; ++j) am = fmaxf(am, fabsf(vv[j]));
        float scale = am * (1.0f / 127.0f);
        float inv = (am > 0.0f) ? (127.0f / am) : 0.0f;
        unsigned int w[3] = {0u, 0u, 0u};
#pragma unroll
        for (int j = 0; j < EMBED_DIM; ++j) {
            int q = (int)rintf(vv[j] * inv);
            q = max(-127, min(127, q));
            unsigned int u = (unsigned int)(q + 128);  // biased, [1,255]
            w[j >> 2] |= u << ((j & 3) * 8);
        }
        uint4 o;
        o.x = w[0]; o.y = w[1]; o.z = w[2]; o.w = __float_as_uint(scale);
        packed[i] = o;
    }

    if (i >= T) return;
    int cur = vox[i];
    int prev = (i == 0) ? -1 : vox[i - 1];
    for (int v = prev + 1; v <= cur; ++v) starts[v] = i;
    if (i == T - 1) {
        for (int v = cur + 1; v <= N; ++v) starts[v] = T;
    }
}

__device__ __forceinline__ float ubyte_f(unsigned int w, int k) {
    // (float)((w >> 8k) & 0xff) -> v_cvt_f32_ubyte{k}
    return (float)((w >> (k * 8)) & 0xffu);
}

// K2: 4 lanes per voxel. Lane `sub` owns token PAIRS (2 consecutive tokens,
// pairs strided by 8), loaded with one int2 (8B-aligned via even base).
// Decode: cvt_f32_ubyte + fma (2 ops/elem); bias removed per-voxel using the
// accumulated scale sum. Partials combined with a 2-step shfl_xor butterfly.
__global__ void pool_normalize_q8_kernel(const uint4* __restrict__ packed,
                                         const int* __restrict__ seg,
                                         const int* __restrict__ starts,
                                         float* __restrict__ out,
                                         int N) {
    int gid = blockIdx.x * blockDim.x + threadIdx.x;
    int v = gid >> 2;
    int sub = gid & 3;
    if (v >= N) return;

    int s = starts[v];
    int e = starts[v + 1];

    float acc[EMBED_DIM];
#pragma unroll
    for (int j = 0; j < EMBED_DIM; ++j) acc[j] = 0.0f;
    float scsum = 0.0f;

    for (int t = (s & ~1) + 2 * sub; t < e; t += 8) {
        int2 sg;
        if (t + 1 < e) {
            sg = *reinterpret_cast<const int2*>(seg + t);  // t even -> 8B aligned
        } else {
            sg.x = seg[t];
            sg.y = sg.x;
        }
        uint4 p0 = packed[sg.x];
        uint4 p1 = packed[sg.y];
        float sc0 = (t >= s) ? __uint_as_float(p0.w) : 0.0f;      // mask pre-range token
        float sc1 = (t + 1 < e) ? __uint_as_float(p1.w) : 0.0f;   // mask tail token
        scsum += sc0 + sc1;
#pragma unroll
        for (int j = 0; j < 4; ++j) {
            acc[j]     += sc0 * ubyte_f(p0.x, j) + sc1 * ubyte_f(p1.x, j);
            acc[4 + j] += sc0 * ubyte_f(p0.y, j) + sc1 * ubyte_f(p1.y, j);
            acc[8 + j] += sc0 * ubyte_f(p0.z, j) + sc1 * ubyte_f(p1.z, j);
        }
    }

    // combine 4 lanes' partials (butterfly keeps result in all lanes)
#pragma unroll
    for (int j = 0; j < EMBED_DIM; ++j) {
        acc[j] += __shfl_xor(acc[j], 1);
        acc[j] += __shfl_xor(acc[j], 2);
    }
    scsum += __shfl_xor(scsum, 1);
    scsum += __shfl_xor(scsum, 2);

    float cnt = (float)(e - s);
    float inv_cnt = 1.0f / fmaxf(cnt, 1.0f);
    float bias = 128.0f * scsum;

    float nrm2 = 0.0f;
#pragma unroll
    for (int j = 0; j < EMBED_DIM; ++j) {
        float m = (acc[j] - bias) * inv_cnt;
        acc[j] = m;
        nrm2 += m * m;
    }
    float inv_nrm = 1.0f / fmaxf(sqrtf(nrm2), EPS);

    if (sub < 3) {
        float4 o;
        o.x = acc[sub * 4 + 0] * inv_nrm;
        o.y = acc[sub * 4 + 1] * inv_nrm;
        o.z = acc[sub * 4 + 2] * inv_nrm;
        o.w = acc[sub * 4 + 3] * inv_nrm;
        float4* orow = reinterpret_cast<float4*>(out + (size_t)v * EMBED_DIM) + sub;
        *orow = o;
    }
}

// Fallback (ws too small): one thread per voxel, fp32 table.
__global__ void pool_normalize_f32_kernel(const float* __restrict__ table,
                                          const int* __restrict__ seg,
                                          const int* __restrict__ starts,
                                          float* __restrict__ out,
                                          int N) {
    int v = blockIdx.x * blockDim.x + threadIdx.x;
    if (v >= N) return;
    int s = starts[v];
    int e = starts[v + 1];
    float acc[EMBED_DIM];
#pragma unroll
    for (int j = 0; j < EMBED_DIM; ++j) acc[j] = 0.0f;
    for (int t = s; t < e; ++t) {
        const float4* row =
            reinterpret_cast<const float4*>(table + (size_t)seg[t] * EMBED_DIM);
        float4 a = row[0], b = row[1], c = row[2];
        acc[0] += a.x; acc[1] += a.y; acc[2]  += a.z; acc[3]  += a.w;
        acc[4] += b.x; acc[5] += b.y; acc[6]  += b.z; acc[7]  += b.w;
        acc[8] += c.x; acc[9] += c.y; acc[10] += c.z; acc[11] += c.w;
    }
    float inv_cnt = 1.0f / fmaxf((float)(e - s), 1.0f);
    float nrm2 = 0.0f;
#pragma unroll
    for (int j = 0; j < EMBED_DIM; ++j) {
        acc[j] *= inv_cnt;
        nrm2 += acc[j] * acc[j];
    }
    float inv_nrm = 1.0f / fmaxf(sqrtf(nrm2), EPS);
#pragma unroll
    for (int j = 0; j < EMBED_DIM; ++j)
        out[(size_t)v * EMBED_DIM + j] = acc[j] * inv_nrm;
}

extern "C" void kernel_launch(void* const* d_in, const int* in_sizes, int n_in,
                              void* d_out, int out_size, void* d_ws, size_t ws_size,
                              hipStream_t stream) {
    const float* table = (const float*)d_in[0];
    const int* seg_ids = (const int*)d_in[1];
    const int* voxel_ids = (const int*)d_in[2];
    int N = out_size / EMBED_DIM;        // 1048576
    int T = in_sizes[1];                 // 8388608
    int rows = in_sizes[0] / EMBED_DIM;  // 50000

    size_t starts_bytes = (size_t)(N + 1) * sizeof(int);
    size_t starts_pad = (starts_bytes + 255) & ~(size_t)255;
    size_t packed_bytes = (size_t)rows * sizeof(uint4);
    bool use_q8 = ws_size >= starts_pad + packed_bytes;

    int* starts = (int*)d_ws;
    uint4* packed = (uint4*)((char*)d_ws + starts_pad);
    float* out = (float*)d_out;

    {
        int block = 256;
        int grid = (T + block - 1) / block;
        prep_kernel<<<grid, block, 0, stream>>>(voxel_ids, starts, table,
                                                use_q8 ? packed : (uint4*)starts,
                                                T, N, use_q8 ? rows : 0);
    }

    if (use_q8) {
        long long total_threads = (long long)N * 4;
        int block = 256;
        int grid = (int)((total_threads + block - 1) / block);
        pool_normalize_q8_kernel<<<grid, block, 0, stream>>>(packed, seg_ids,
                                                             starts, out, N);
    } else {
        int block = 256;
        int grid = (N + block - 1) / block;
        pool_normalize_f32_kernel<<<grid, block, 0, stream>>>(table, seg_ids,
                                                              starts, out, N);
    }
}

// Round 7
// 67.094 us; speedup vs baseline: 5.8300x; 1.1051x over previous
//
#include <hip/hip_runtime.h>
#include <hip/hip_bf16.h>
#include <hip/hip_fp16.h>

#define EMBED_DIM 12
#define EPS 1e-12f
#define ROW_STRIDE_U32 8   // 32 B padded row: 12 f16 (24B) + 8B pad

// K1 (fused prep): CSR offsets from sorted voxel_ids + convert table rows to
// f16 (12 halves, 32B-padded). Row index `rows` is an all-zero sentinel used
// for tail masking in K2.
__global__ void prep_kernel(const int* __restrict__ vox,
                            int* __restrict__ starts,
                            const float* __restrict__ tab,
                            unsigned int* __restrict__ tp,
                            int T, int N, int rows) {
    int i = blockIdx.x * blockDim.x + threadIdx.x;

    if (i <= rows) {
        float vv[EMBED_DIM];
        if (i < rows) {
            const float4* rp = reinterpret_cast<const float4*>(tab + (size_t)i * EMBED_DIM);
            float4 a = rp[0], b = rp[1], c = rp[2];
            vv[0] = a.x; vv[1] = a.y; vv[2]  = a.z; vv[3]  = a.w;
            vv[4] = b.x; vv[5] = b.y; vv[6]  = b.z; vv[7]  = b.w;
            vv[8] = c.x; vv[9] = c.y; vv[10] = c.z; vv[11] = c.w;
        } else {
#pragma unroll
            for (int j = 0; j < EMBED_DIM; ++j) vv[j] = 0.0f;
        }
        unsigned int w[6];
#pragma unroll
        for (int j = 0; j < 6; ++j) {
            __half2 h = __floats2half2_rn(vv[2 * j], vv[2 * j + 1]);
            w[j] = *reinterpret_cast<unsigned int*>(&h);
        }
        unsigned int* dst = tp + (size_t)i * ROW_STRIDE_U32;
        uint4 lo; lo.x = w[0]; lo.y = w[1]; lo.z = w[2]; lo.w = w[3];
        *reinterpret_cast<uint4*>(dst) = lo;
        uint2 hi; hi.x = w[4]; hi.y = w[5];
        *reinterpret_cast<uint2*>(dst + 4) = hi;
    }

    if (i >= T) return;
    int cur = vox[i];
    int prev = (i == 0) ? -1 : vox[i - 1];
    for (int v = prev + 1; v <= cur; ++v) starts[v] = i;
    if (i == T - 1) {
        for (int v = cur + 1; v <= N; ++v) starts[v] = T;
    }
}

__device__ __forceinline__ __half2 u2h2(unsigned int u) {
    return *reinterpret_cast<__half2*>(&u);
}

// K2: 4 lanes per voxel, tokens strided by 4, 2-deep unroll (R4 structure).
// Accumulation = 6 packed-f16 adds per token; tail handled by selecting the
// sentinel zero row (one cndmask, branch-free body).
__global__ void pool_normalize_f16_kernel(const unsigned int* __restrict__ tp,
                                          const int* __restrict__ seg,
                                          const int* __restrict__ starts,
                                          float* __restrict__ out,
                                          int N, int zrow) {
    int gid = blockIdx.x * blockDim.x + threadIdx.x;
    int v = gid >> 2;
    int sub = gid & 3;
    if (v >= N) return;

    int s = starts[v];
    int e = starts[v + 1];

    __half2 acc[6];
#pragma unroll
    for (int j = 0; j < 6; ++j) acc[j] = __floats2half2_rn(0.0f, 0.0f);

    for (int t = s + sub; t < e; t += 8) {
        int sid0 = seg[t];
        int t2 = t + 4;
        int ta = min(t2, e - 1);
        int sid1 = seg[ta];
        sid1 = (t2 < e) ? sid1 : zrow;   // sentinel zero row: no contribution

        const unsigned int* r0 = tp + (size_t)sid0 * ROW_STRIDE_U32;
        const unsigned int* r1 = tp + (size_t)sid1 * ROW_STRIDE_U32;
        uint4 a0 = *reinterpret_cast<const uint4*>(r0);
        uint2 b0 = *reinterpret_cast<const uint2*>(r0 + 4);
        uint4 a1 = *reinterpret_cast<const uint4*>(r1);
        uint2 b1 = *reinterpret_cast<const uint2*>(r1 + 4);

        acc[0] = __hadd2(acc[0], u2h2(a0.x));
        acc[1] = __hadd2(acc[1], u2h2(a0.y));
        acc[2] = __hadd2(acc[2], u2h2(a0.z));
        acc[3] = __hadd2(acc[3], u2h2(a0.w));
        acc[4] = __hadd2(acc[4], u2h2(b0.x));
        acc[5] = __hadd2(acc[5], u2h2(b0.y));
        acc[0] = __hadd2(acc[0], u2h2(a1.x));
        acc[1] = __hadd2(acc[1], u2h2(a1.y));
        acc[2] = __hadd2(acc[2], u2h2(a1.z));
        acc[3] = __hadd2(acc[3], u2h2(a1.w));
        acc[4] = __hadd2(acc[4], u2h2(b1.x));
        acc[5] = __hadd2(acc[5], u2h2(b1.y));
    }

    // combine 4 lanes' packed partials (12 shfl + 12 packed adds)
#pragma unroll
    for (int j = 0; j < 6; ++j) {
        unsigned int u = *reinterpret_cast<unsigned int*>(&acc[j]);
        unsigned int u1 = (unsigned int)__shfl_xor((int)u, 1);
        acc[j] = __hadd2(acc[j], u2h2(u1));
        unsigned int u2x = *reinterpret_cast<unsigned int*>(&acc[j]);
        unsigned int u2 = (unsigned int)__shfl_xor((int)u2x, 2);
        acc[j] = __hadd2(acc[j], u2h2(u2));
    }

    float m[EMBED_DIM];
#pragma unroll
    for (int j = 0; j < 6; ++j) {
        m[2 * j]     = __low2float(acc[j]);
        m[2 * j + 1] = __high2float(acc[j]);
    }

    float cnt = (float)(e - s);
    float inv_cnt = 1.0f / fmaxf(cnt, 1.0f);

    float nrm2 = 0.0f;
#pragma unroll
    for (int j = 0; j < EMBED_DIM; ++j) {
        m[j] *= inv_cnt;
        nrm2 += m[j] * m[j];
    }
    float inv_nrm = 1.0f / fmaxf(sqrtf(nrm2), EPS);

    if (sub < 3) {
        float4 o;
        o.x = m[sub * 4 + 0] * inv_nrm;
        o.y = m[sub * 4 + 1] * inv_nrm;
        o.z = m[sub * 4 + 2] * inv_nrm;
        o.w = m[sub * 4 + 3] * inv_nrm;
        float4* orow = reinterpret_cast<float4*>(out + (size_t)v * EMBED_DIM) + sub;
        *orow = o;
    }
}

// Fallback (ws too small): one thread per voxel, fp32 table.
__global__ void pool_normalize_f32_kernel(const float* __restrict__ table,
                                          const int* __restrict__ seg,
                                          const int* __restrict__ starts,
                                          float* __restrict__ out,
                                          int N) {
    int v = blockIdx.x * blockDim.x + threadIdx.x;
    if (v >= N) return;
    int s = starts[v];
    int e = starts[v + 1];
    float acc[EMBED_DIM];
#pragma unroll
    for (int j = 0; j < EMBED_DIM; ++j) acc[j] = 0.0f;
    for (int t = s; t < e; ++t) {
        const float4* row =
            reinterpret_cast<const float4*>(table + (size_t)seg[t] * EMBED_DIM);
        float4 a = row[0], b = row[1], c = row[2];
        acc[0] += a.x; acc[1] += a.y; acc[2]  += a.z; acc[3]  += a.w;
        acc[4] += b.x; acc[5] += b.y; acc[6]  += b.z; acc[7]  += b.w;
        acc[8] += c.x; acc[9] += c.y; acc[10] += c.z; acc[11] += c.w;
    }
    float inv_cnt = 1.0f / fmaxf((float)(e - s), 1.0f);
    float nrm2 = 0.0f;
#pragma unroll
    for (int j = 0; j < EMBED_DIM; ++j) {
        acc[j] *= inv_cnt;
        nrm2 += acc[j] * acc[j];
    }
    float inv_nrm = 1.0f / fmaxf(sqrtf(nrm2), EPS);
#pragma unroll
    for (int j = 0; j < EMBED_DIM; ++j)
        out[(size_t)v * EMBED_DIM + j] = acc[j] * inv_nrm;
}

extern "C" void kernel_launch(void* const* d_in, const int* in_sizes, int n_in,
                              void* d_out, int out_size, void* d_ws, size_t ws_size,
                              hipStream_t stream) {
    const float* table = (const float*)d_in[0];
    const int* seg_ids = (const int*)d_in[1];
    const int* voxel_ids = (const int*)d_in[2];
    int N = out_size / EMBED_DIM;        // 1048576
    int T = in_sizes[1];                 // 8388608
    int rows = in_sizes[0] / EMBED_DIM;  // 50000

    size_t starts_bytes = (size_t)(N + 1) * sizeof(int);
    size_t starts_pad = (starts_bytes + 255) & ~(size_t)255;
    size_t tp_bytes = (size_t)(rows + 1) * ROW_STRIDE_U32 * sizeof(unsigned int);
    bool use_f16 = ws_size >= starts_pad + tp_bytes;

    int* starts = (int*)d_ws;
    unsigned int* tp = (unsigned int*)((char*)d_ws + starts_pad);
    float* out = (float*)d_out;

    {
        int block = 256;
        int grid = (T + block - 1) / block;
        prep_kernel<<<grid, block, 0, stream>>>(voxel_ids, starts, table,
                                                use_f16 ? tp : (unsigned int*)starts,
                                                T, N, use_f16 ? rows : -1);
    }

    if (use_f16) {
        long long total_threads = (long long)N * 4;
        int block = 256;
        int grid = (int)((total_threads + block - 1) / block);
        pool_normalize_f16_kernel<<<grid, block, 0, stream>>>(tp, seg_ids,
                                                              starts, out, N, rows);
    } else {
        int block = 256;
        int grid = (N + block - 1) / block;
        pool_normalize_f32_kernel<<<grid, block, 0, stream>>>(table, seg_ids,
                                                              starts, out, N);
    }
}